// Round 8
// baseline (166.515 us; speedup 1.0000x reference)
//
#include <hip/hip_runtime.h>
#include <stdint.h>

typedef __bf16 bf16x8 __attribute__((ext_vector_type(8)));
typedef __bf16 bf16x4v __attribute__((ext_vector_type(4)));
typedef float  f32x16 __attribute__((ext_vector_type(16)));
typedef float  f32x4t __attribute__((ext_vector_type(4)));
typedef unsigned int u32x2 __attribute__((ext_vector_type(2)));

// ---- ws layout (bytes) ----
#define WS_W1S 0            // 32 chunks  * 1 KB = 32 KB   W1e fragment-swizzled
#define WS_W2S 32768        // 128 chunks * 1 KB = 128 KB  W2 fragment-swizzled
#define WS_R   163840       // 4*256*256 f32 = 1 MiB   Rt[b][n][o] (incl. b1)
#define WS_CT  1212416      // 4*256*256 bf16 = 512 KB Ct[b][m][o]

// ---------------- merged pre-kernel: weights + rank-1 + out-init ----------
__global__ __launch_bounds__(256) void prep_all(
    const float* __restrict__ W1, const float* __restrict__ b1,
    const float* __restrict__ W2, const float* __restrict__ node,
    const float* __restrict__ b3, __bf16* __restrict__ w1s,
    __bf16* __restrict__ w2s, float* __restrict__ Rt,
    __bf16* __restrict__ Ctb, float* __restrict__ out) {
    __shared__ float nds[128 * 4];
    const int blk = blockIdx.x;
    if (blk >= 296) {                         // ---- out-init: 256 blk x 1KB ----
        float v = b3[0];
        float4 f4 = make_float4(v, v, v, v);
        *(float4*)(out + (blk - 296) * 1024 + threadIdx.x * 4) = f4;
        return;
    }
    if (blk < 40) {                           // ---- weight swizzle part ----
        int t = blk * 256 + threadIdx.x;      // 40*256 = 160 chunks * 64 lanes
        int chunk = t >> 6, lane = t & 63;
        if (chunk < 128) {                    // W2: 4 wid x 16 ks x 2 mb
            int wid = chunk >> 5, ks = (chunk >> 1) & 15, mb = chunk & 1;
            int o = wid * 64 + mb * 32 + (lane & 31);
            int k = ks * 16 + (lane >> 5) * 8;
            const float* src = W2 + o * 256 + k;
            __bf16* dst = w2s + chunk * 512 + lane * 8;
#pragma unroll
            for (int j = 0; j < 8; ++j) dst[j] = (__bf16)src[j];
        } else if (chunk < 160) {             // W1e: 4 wid x 4 ks x 2 mb
            int c1 = chunk - 128;
            int wid = c1 >> 3, ks = (c1 >> 1) & 3, mb = c1 & 1;
            int o = wid * 64 + mb * 32 + (lane & 31);
            int k = ks * 16 + (lane >> 5) * 8;
            const float* src = W1 + o * 320 + k;
            __bf16* dst = w1s + c1 * 512 + lane * 8;
#pragma unroll
            for (int j = 0; j < 8; ++j) dst[j] = (__bf16)src[j];
        }
        return;
    }
    // ---- rank-1 part: rcb = b*64 + jg, 4 j per thread, o = tid ----
    const int rcb = blk - 40;
    const int b = rcb >> 6, j0 = (rcb & 63) << 2;
    const int o = threadIdx.x;
    if (o < 128)
        *(float4*)&nds[o * 4] = *(const float4*)(node + b * 32768 + o * 256 + j0);
    __syncthreads();
    float aR[4] = {0.f, 0.f, 0.f, 0.f};
    float aC[4] = {0.f, 0.f, 0.f, 0.f};
    const float* wr = W1 + o * 320 + 64;
    const float* wc = W1 + o * 320 + 192;
    for (int c4 = 0; c4 < 32; ++c4) {
        float4 wrv = *(const float4*)(wr + c4 * 4);
        float4 wcv = *(const float4*)(wc + c4 * 4);
        const float* wrp = (const float*)&wrv;
        const float* wcp = (const float*)&wcv;
#pragma unroll
        for (int r = 0; r < 4; ++r) {
            f32x4t n4 = *(const f32x4t*)&nds[(c4 * 4 + r) * 4];
#pragma unroll
            for (int q = 0; q < 4; ++q) {
                aR[q] = fmaf(wrp[r], n4[q], aR[q]);
                aC[q] = fmaf(wcp[r], n4[q], aC[q]);
            }
        }
    }
    float bb = b1[o];
#pragma unroll
    for (int j = 0; j < 4; ++j) {
        int idx = ((b * 256 + j0 + j) << 8) + o;
        Rt[idx] = aR[j] + bb;
        Ctb[idx] = (__bf16)aC[j];
    }
}

// ---------------- main fused kernel ----------------
// R8 = R7 (W2-half LDS-resident, 8 fat waves = 2 row-groups x 4 och-groups,
// 1 block/CU, atomics epilogue) + PHASE-OFFSET PIPELINE. R7 post-mortem: at
// lockstep, both waves/SIMD sit in the same phase -> co-stall (MfmaUtil 30%,
// nothing saturated). Here group G(rw) alternates roles per step, offset by
// one: every step each SIMD hosts one A-wave [stage+L1+epi1, VALU-heavy] and
// one B-wave [L2 64-MFMA, matrix-heavy] -> A's VALU runs under B's MFMA.
// 17 steps/block (1 idle head/tail per group), 2 barriers/step. Per-wave
// economics, LDS layout, fragment math identical to R7.
// Schedule: wave rw does A(row k) at step s=2k+rw, B(row k) at s=2k+rw+1.
// A2q[0] issued at A-end, consumed at B-start (lives across 1 barrier).
// Budget: (512,2) = 256 unified regs/wave. Live ~225 peak (acc 64 + A1 32 +
// CvR 32 + A2q 64 + pf 16 + transients). SPILL TRIPWIRE: VGPR < 110 or
// WRITE_SIZE >> 10 MB (atomics alone ~4 MB).
// Raw LDS-only barriers; hazards: lds_e[rw] write(A sub1) -> mid-bar ->
// L1 reads(A sub2) -> end-bar; next write is wave's next A (2 steps later).
// h1[rw] write(A sub2, epi1) -> end-bar -> B reads(next step) -> end-bar ->
// next A sub2 write. Groups never touch each other's buffers; w2lds is
// read-only after prologue (ordered by first step's barriers).
__device__ __forceinline__ void lds_barrier() {
    __builtin_amdgcn_sched_barrier(0);
    asm volatile("s_waitcnt lgkmcnt(0)" ::: "memory");
    __builtin_amdgcn_s_barrier();
    __builtin_amdgcn_sched_barrier(0);
}

__global__ __launch_bounds__(512, 2) void fused_main(
    const float* __restrict__ edge, const __bf16* __restrict__ w1s,
    const __bf16* __restrict__ w2s, const float* __restrict__ Rt,
    const __bf16* __restrict__ Ctb, const float* __restrict__ b2,
    const float* __restrict__ W3, const float* __restrict__ b3,
    float* __restrict__ out) {
    __shared__ __bf16 w2lds[32768];              // 64 KB: W2 ksg 8..15, chunk-linear
    __shared__ unsigned int lds_e[128 * 34];     // 17.4 KB: 2 groups x [64 m][32 ep]
    __shared__ unsigned int lds_h1[2][64 * 140]; // 71.7 KB: per-group h1, stride 140 dw
    __shared__ float lds_c[512];                 // 2 KB: [0..255]=b2, [256..511]=W3

    const int tid = threadIdx.x;
    const int wid8 = tid >> 6;       // 0..7
    const int og   = wid8 & 3;       // och group (64 och)
    const int rw   = wid8 >> 2;      // row-group (phase offset group)
    const int lane = tid & 63;
    const int p31  = lane & 31;
    const int hi   = lane >> 5;
    const int obase = og << 6;

    const int blk = blockIdx.x;      // 256 = 4b x 4m x 16 n-groups
    const int b   = blk >> 6;
    const int m0  = ((blk >> 4) & 3) << 6;
    const int n0  = (blk & 15) << 4; // 16 rows per block

    lds_c[tid] = (tid < 256) ? b2[tid] : W3[tid - 256];

    // ---- stage resident W2 half (ksg 8..15) into LDS, ONCE ----
    {
        bf16x8 wt[8];
#pragma unroll
        for (int i = 0; i < 8; ++i) {
            int rc = wid8 * 8 + i;                     // resident chunk 0..63
            int mb = rc & 1, k8 = (rc >> 1) & 7, wg = rc >> 4;
            int schunk = (((wg << 4) + 8 + k8) << 1) + mb;
            wt[i] = *(const bf16x8*)(w2s + schunk * 512 + (lane << 3));
        }
#pragma unroll
        for (int i = 0; i < 8; ++i)
            *(bf16x8*)(w2lds + (wid8 * 8 + i) * 512 + (lane << 3)) = wt[i];
    }

    const float4* eg = (const float4*)edge;
    const int tid8 = tid & 255;      // within-group thread
    const int a_   = tid8 & 15;      // m-quad
    const int epb  = tid8 >> 4;      // 0..15 e-pair group
    float4 pf[4];

#define PREFETCH(nn)                                                        \
    {                                                                       \
        _Pragma("unroll")                                                   \
        for (int r = 0; r < 2; ++r) {                                       \
            int ep = r * 16 + epb;                                          \
            int f4 = (b * 64 + ep * 2) * 16384 + (nn) * 64 + (m0 >> 2) + a_;\
            pf[r * 2]     = eg[f4];                                         \
            pf[r * 2 + 1] = eg[f4 + 16384];                                 \
        }                                                                   \
    }

    // streamed W2 quarter (ksg 0..7): chunk = ((og*16 + q*4 + ksl)*2 + mb)
#define LOAD_Q(bf, q)                                                       \
    {                                                                       \
        _Pragma("unroll")                                                   \
        for (int ksl = 0; ksl < 4; ++ksl)                                   \
            _Pragma("unroll")                                               \
            for (int mb = 0; mb < 2; ++mb)                                  \
                A2q[bf][ksl][mb] = *(const bf16x8*)(w2_s +                  \
                    ((((og << 4) + (q) * 4 + ksl) << 1) + mb) * 512 + (lane << 3)); \
    }

    PREFETCH(n0 + rw);               // this wave's row k=0

    // ---- hoisted it-invariant Ct fragments (32 regs; row-independent) ----
    bf16x4v CvR[8][2];
#pragma unroll
    for (int mb = 0; mb < 2; ++mb)
#pragma unroll
        for (int rg = 0; rg < 4; ++rg)
#pragma unroll
            for (int nb = 0; nb < 2; ++nb)
                CvR[mb * 4 + rg][nb] = *(const bf16x4v*)(Ctb +
                    ((b * 256 + m0 + nb * 32 + p31) << 8) + obase + mb * 32 + 8 * rg + 4 * hi);

    // ---- A1 (W1e) fragments: loop-invariant, persist (32 regs) ----
    bf16x8 A1[2][4];
#pragma unroll
    for (int mb = 0; mb < 2; ++mb)
#pragma unroll
        for (int ks = 0; ks < 4; ++ks)
            A1[mb][ks] = *(const bf16x8*)(w1s +
                ((((og << 2) + ks) << 1) + mb) * 512 + (lane << 3));

    f32x16 acc[2][2];
    bf16x8 A2q[2][4][2];
#pragma unroll 1
    for (int s = 0; s < 17; ++s) {
        const int ph = (s + rw) & 1;          // 0 = A-phase for this wave
        const int kA = (s - rw) >> 1;         // A row index (ph==0)
        const int kB = (s - rw - 1) >> 1;     // B row index (ph==1)
        const bool doA = (ph == 0) && (kA < 8);
        const bool doB = (ph == 1) && (kB >= 0);

        // opaque per-step values: defeat LICM/CSE of streamed W2 loads and
        // resident LDS reads (hoisting either = reg blowup -> spill)
        uint64_t w2a = (uint64_t)w2s;
        asm volatile("" : "+s"(w2a));
        const __bf16* w2_s = (const __bf16*)w2a;
        int koff = 0;
        asm volatile("" : "+v"(koff));

        // ================= sub-phase 1 =================
        if (doA) {
            // ---- stage pf -> lds_e[rw] (transpose to [m][e-pair], bf16) ----
#pragma unroll
            for (int r = 0; r < 2; ++r) {
                int ep = r * 16 + epb;
                const float* p0 = (const float*)&pf[r * 2];
                const float* p1 = (const float*)&pf[r * 2 + 1];
#pragma unroll
                for (int i = 0; i < 4; ++i) {
                    union { __bf16 h[2]; unsigned int u; } t;
                    t.h[0] = (__bf16)p0[i];
                    t.h[1] = (__bf16)p1[i];
                    lds_e[(rw * 64 + a_ * 4 + i) * 34 + ep] = t.u;
                }
            }
            // next-row HBM prefetch (2 steps of slack, flies over barriers)
            if (kA < 7) PREFETCH(n0 + (kA + 1) * 2 + rw);
            // acc = Ct preload (MFMA C-operand is a free adder)
#pragma unroll
            for (int mb = 0; mb < 2; ++mb)
#pragma unroll
                for (int nb = 0; nb < 2; ++nb)
#pragma unroll
                    for (int rg = 0; rg < 4; ++rg)
#pragma unroll
                        for (int rr = 0; rr < 4; ++rr)
                            acc[mb][nb][rg * 4 + rr] = (float)CvR[mb * 4 + rg][nb][rr];
        }
        if (doB) {
            // acc = b2 preload
#pragma unroll
            for (int mb = 0; mb < 2; ++mb)
#pragma unroll
                for (int rg = 0; rg < 4; ++rg) {
                    f32x4t b2v = *(const f32x4t*)&lds_c[obase + mb * 32 + 8 * rg + 4 * hi];
#pragma unroll
                    for (int nb = 0; nb < 2; ++nb)
#pragma unroll
                        for (int rr = 0; rr < 4; ++rr)
                            acc[mb][nb][rg * 4 + rr] = b2v[rr];
                }
            // ---- L2 streamed half: ksg 0..7 (A2q[0] issued at A-end) ----
            __builtin_amdgcn_s_setprio(1);
#pragma unroll
            for (int q = 0; q < 2; ++q) {
                if (q == 0) LOAD_Q(1, 1);
#pragma unroll
                for (int ksl = 0; ksl < 4; ++ksl) {
                    const int ksg = q * 4 + ksl;
                    bf16x8 B2[2];
#pragma unroll
                    for (int nb = 0; nb < 2; ++nb)
                        B2[nb] = *(const bf16x8*)&lds_h1[rw][(nb * 32 + p31) * 140 + ksg * 8 + hi * 4];
#pragma unroll
                    for (int mb = 0; mb < 2; ++mb) {
                        acc[mb][0] = __builtin_amdgcn_mfma_f32_32x32x16_bf16(A2q[q][ksl][mb], B2[0], acc[mb][0], 0, 0, 0);
                        acc[mb][1] = __builtin_amdgcn_mfma_f32_32x32x16_bf16(A2q[q][ksl][mb], B2[1], acc[mb][1], 0, 0, 0);
                    }
                }
            }
            __builtin_amdgcn_s_setprio(0);
        }
        lds_barrier();

        // ================= sub-phase 2 =================
        if (doA) {
            const int n_r = n0 + kA * 2 + rw;
            const int nRow = (b * 256 + n_r) << 8;
            // Rt row issued first: ~200-300cy L2 latency hides under L1 MFMAs
            f32x4t Rv[2][4];
#pragma unroll
            for (int mb = 0; mb < 2; ++mb)
#pragma unroll
                for (int rg = 0; rg < 4; ++rg)
                    Rv[mb][rg] = *(const f32x4t*)(Rt + nRow + obase + mb * 32 + 8 * rg + 4 * hi);
            // ---- layer 1: W1e(64K) @ edge ----
            __builtin_amdgcn_s_setprio(1);
#pragma unroll
            for (int ks = 0; ks < 4; ++ks) {
                bf16x8 B1[2];
#pragma unroll
                for (int nb = 0; nb < 2; ++nb) {
                    union { u32x2 d[2]; bf16x8 v; } bb;
                    const unsigned int* base = &lds_e[(rw * 64 + nb * 32 + p31) * 34 + ks * 8 + hi * 4];
                    bb.d[0] = *(const u32x2*)base;
                    bb.d[1] = *(const u32x2*)(base + 2);
                    B1[nb] = bb.v;
                }
#pragma unroll
                for (int mb = 0; mb < 2; ++mb) {
                    acc[mb][0] = __builtin_amdgcn_mfma_f32_32x32x16_bf16(A1[mb][ks], B1[0], acc[mb][0], 0, 0, 0);
                    acc[mb][1] = __builtin_amdgcn_mfma_f32_32x32x16_bf16(A1[mb][ks], B1[1], acc[mb][1], 0, 0, 0);
                }
            }
            __builtin_amdgcn_s_setprio(0);
            // ---- epilogue 1: relu(acc + Rt) -> lds_h1[rw] ----
#pragma unroll
            for (int mb = 0; mb < 2; ++mb) {
#pragma unroll
                for (int rg = 0; rg < 4; ++rg) {
                    int och = obase + mb * 32 + 8 * rg + 4 * hi;
                    f32x4t Rvv = Rv[mb][rg];
#pragma unroll
                    for (int nb = 0; nb < 2; ++nb) {
                        int pix = nb * 32 + p31;
                        union { __bf16 h[4]; u32x2 u; } t;
#pragma unroll
                        for (int rr = 0; rr < 4; ++rr) {
                            float v = acc[mb][nb][rg * 4 + rr] + Rvv[rr];
                            t.h[rr] = (__bf16)fmaxf(v, 0.f);
                        }
                        *(u32x2*)&lds_h1[rw][pix * 140 + (och >> 1)] = t.u;
                    }
                }
            }
            // streamed W2 quarter-0 prefetch for next step's B (lives across bar)
            LOAD_Q(0, 0);
        }
        if (doB) {
            // ---- L2 resident half: ksg 8..15 from w2lds ----
            __builtin_amdgcn_s_setprio(1);
#pragma unroll
            for (int k8 = 0; k8 < 8; ++k8) {
                const int ksg = 8 + k8;
                bf16x8 A2r[2];
#pragma unroll
                for (int mb = 0; mb < 2; ++mb)
                    A2r[mb] = *(const bf16x8*)(w2lds +
                        (((og * 8 + k8) * 2 + mb) * 512 + koff) + (lane << 3));
                bf16x8 B2[2];
#pragma unroll
                for (int nb = 0; nb < 2; ++nb)
                    B2[nb] = *(const bf16x8*)&lds_h1[rw][(nb * 32 + p31) * 140 + ksg * 8 + hi * 4];
#pragma unroll
                for (int mb = 0; mb < 2; ++mb) {
                    acc[mb][0] = __builtin_amdgcn_mfma_f32_32x32x16_bf16(A2r[mb], B2[0], acc[mb][0], 0, 0, 0);
                    acc[mb][1] = __builtin_amdgcn_mfma_f32_32x32x16_bf16(A2r[mb], B2[1], acc[mb][1], 0, 0, 0);
                }
            }
            __builtin_amdgcn_s_setprio(0);
            // ---- epilogue 2: relu, dot W3, shfl-combine, atomicAdd out ----
            float part0 = 0.f, part1 = 0.f;
#pragma unroll
            for (int mb = 0; mb < 2; ++mb) {
#pragma unroll
                for (int rg = 0; rg < 4; ++rg) {
                    int och = obase + mb * 32 + 8 * rg + 4 * hi;
                    f32x4t w3v = *(const f32x4t*)&lds_c[256 + och];
#pragma unroll
                    for (int rr = 0; rr < 4; ++rr) {
                        float h0 = fmaxf(acc[mb][0][rg * 4 + rr], 0.f);
                        float h1v = fmaxf(acc[mb][1][rg * 4 + rr], 0.f);
                        part0 = fmaf(w3v[rr], h0, part0);
                        part1 = fmaf(w3v[rr], h1v, part1);
                    }
                }
            }
            part0 += __shfl_xor(part0, 32);
            part1 += __shfl_xor(part1, 32);
            {
                const int n_r = n0 + kB * 2 + rw;
                int pix = hi ? (32 + p31) : p31;
                float v = hi ? part1 : part0;
                atomicAdd(&out[((b * 256 + n_r) << 8) + m0 + pix], v);
            }
        }
        lds_barrier();
    }
#undef PREFETCH
#undef LOAD_Q
}

extern "C" void kernel_launch(void* const* d_in, const int* in_sizes, int n_in,
                              void* d_out, int out_size, void* d_ws, size_t ws_size,
                              hipStream_t stream) {
    const float* edge = (const float*)d_in[0];
    const float* node = (const float*)d_in[1];
    const float* W1   = (const float*)d_in[2];
    const float* b1   = (const float*)d_in[3];
    const float* W2   = (const float*)d_in[4];
    const float* b2   = (const float*)d_in[5];
    const float* W3   = (const float*)d_in[6];
    const float* b3   = (const float*)d_in[7];
    char* ws = (char*)d_ws;
    __bf16* w1s = (__bf16*)(ws + WS_W1S);
    __bf16* w2s = (__bf16*)(ws + WS_W2S);
    float*  Rt  = (float*)(ws + WS_R);
    __bf16* Ctb = (__bf16*)(ws + WS_CT);
    float* outp = (float*)d_out;

    prep_all<<<552, 256, 0, stream>>>(W1, b1, W2, node, b3, w1s, w2s, Rt, Ctb, outp);
    fused_main<<<256, 512, 0, stream>>>(edge, w1s, w2s, Rt, Ctb, b2, W3, b3, outp);
}

// Round 9
// 146.086 us; speedup vs baseline: 1.1398x; 1.1398x over previous
//
#include <hip/hip_runtime.h>
#include <stdint.h>

typedef __bf16 bf16x8 __attribute__((ext_vector_type(8)));
typedef __bf16 bf16x4v __attribute__((ext_vector_type(4)));
typedef float  f32x16 __attribute__((ext_vector_type(16)));
typedef float  f32x4t __attribute__((ext_vector_type(4)));
typedef unsigned int u32x2 __attribute__((ext_vector_type(2)));

// ---- ws layout (bytes) ----
#define WS_W1S 0            // 32 chunks  * 1 KB = 32 KB   W1e fragment-swizzled
#define WS_W2S 32768        // 128 chunks * 1 KB = 128 KB  W2 fragment-swizzled
#define WS_R   163840       // 4*256*256 f32 = 1 MiB   Rt[b][n][o] (incl. b1)
#define WS_CT  1212416      // 4*256*256 bf16 = 512 KB Ct[b][m][o]

// ---------------- merged pre-kernel: weights + rank-1 + out-init ----------
// blocks 0..39: weight swizzle; 40..167: rank-1 R/C (8 j/thread, 128 blocks:
// W1 L2 re-read traffic halved vs 4 j/thread -- traffic = blocks * 256 KB);
// 168..423: out = b3 init (fused accumulates via atomicAdd).
__global__ __launch_bounds__(256) void prep_all(
    const float* __restrict__ W1, const float* __restrict__ b1,
    const float* __restrict__ W2, const float* __restrict__ node,
    const float* __restrict__ b3, __bf16* __restrict__ w1s,
    __bf16* __restrict__ w2s, float* __restrict__ Rt,
    __bf16* __restrict__ Ctb, float* __restrict__ out) {
    __shared__ float nds[128 * 8];
    const int blk = blockIdx.x;
    if (blk >= 168) {                         // ---- out-init: 256 blk x 1KB ----
        float v = b3[0];
        float4 f4 = make_float4(v, v, v, v);
        *(float4*)(out + (blk - 168) * 1024 + threadIdx.x * 4) = f4;
        return;
    }
    if (blk < 40) {                           // ---- weight swizzle part ----
        int t = blk * 256 + threadIdx.x;      // 40*256 = 160 chunks * 64 lanes
        int chunk = t >> 6, lane = t & 63;
        if (chunk < 128) {                    // W2: 4 wid x 16 ks x 2 mb
            int wid = chunk >> 5, ks = (chunk >> 1) & 15, mb = chunk & 1;
            int o = wid * 64 + mb * 32 + (lane & 31);
            int k = ks * 16 + (lane >> 5) * 8;
            const float* src = W2 + o * 256 + k;
            __bf16* dst = w2s + chunk * 512 + lane * 8;
#pragma unroll
            for (int j = 0; j < 8; ++j) dst[j] = (__bf16)src[j];
        } else if (chunk < 160) {             // W1e: 4 wid x 4 ks x 2 mb
            int c1 = chunk - 128;
            int wid = c1 >> 3, ks = (c1 >> 1) & 3, mb = c1 & 1;
            int o = wid * 64 + mb * 32 + (lane & 31);
            int k = ks * 16 + (lane >> 5) * 8;
            const float* src = W1 + o * 320 + k;
            __bf16* dst = w1s + c1 * 512 + lane * 8;
#pragma unroll
            for (int j = 0; j < 8; ++j) dst[j] = (__bf16)src[j];
        }
        return;
    }
    // ---- rank-1 part: rcb = b*32 + jg, 8 j per thread, o = tid ----
    const int rcb = blk - 40;                 // 0..127
    const int b = rcb >> 5, j0 = (rcb & 31) << 3;
    const int o = threadIdx.x;
    {
        int c = o >> 1, jh = (o & 1) * 4;
        *(float4*)&nds[c * 8 + jh] = *(const float4*)(node + b * 32768 + c * 256 + j0 + jh);
    }
    __syncthreads();
    float aR[8], aC[8];
#pragma unroll
    for (int j = 0; j < 8; ++j) { aR[j] = 0.f; aC[j] = 0.f; }
    const float* wr = W1 + o * 320 + 64;
    const float* wc = W1 + o * 320 + 192;
    for (int c4 = 0; c4 < 32; ++c4) {
        float4 wrv = *(const float4*)(wr + c4 * 4);
        float4 wcv = *(const float4*)(wc + c4 * 4);
        const float* wrp = (const float*)&wrv;
        const float* wcp = (const float*)&wcv;
#pragma unroll
        for (int r = 0; r < 4; ++r) {
            const f32x4t* nrow = (const f32x4t*)&nds[(c4 * 4 + r) * 8];
            f32x4t n0 = nrow[0], n1 = nrow[1];
#pragma unroll
            for (int q = 0; q < 4; ++q) {
                aR[q]     = fmaf(wrp[r], n0[q], aR[q]);
                aR[q + 4] = fmaf(wrp[r], n1[q], aR[q + 4]);
                aC[q]     = fmaf(wcp[r], n0[q], aC[q]);
                aC[q + 4] = fmaf(wcp[r], n1[q], aC[q + 4]);
            }
        }
    }
    float bb = b1[o];
#pragma unroll
    for (int j = 0; j < 8; ++j) {
        int idx = ((b * 256 + j0 + j) << 8) + o;
        Rt[idx] = aR[j] + bb;
        Ctb[idx] = (__bf16)aC[j];
    }
}

// ---------------- main fused kernel ----------------
// R9 = R7 exactly (the measured optimum: 55.9 us), prologue reordered so the
// HBM edge PREFETCH issues before the W2->LDS staging (longest latency first).
// Design-space map (R1..R8): fat 64-och waves mandatory (R5: thin waves +35%);
// 2 waves/SIMD is the unified-RF cap (R1/R4: any lower reg budget = 28-104 MB
// scratch); minimum barrier count wins (R8: phase-offset doubled barriers,
// +32%). W2 ksg 8..15 resident in LDS (64 KB staged once -> W2 L2 stream
// 256->64 KB/CU-iter, the R7 +9%); atomics epilogue w/ out pre-init.
__device__ __forceinline__ void lds_barrier() {
    __builtin_amdgcn_sched_barrier(0);
    asm volatile("s_waitcnt lgkmcnt(0)" ::: "memory");
    __builtin_amdgcn_s_barrier();
    __builtin_amdgcn_sched_barrier(0);
}

__global__ __launch_bounds__(512, 2) void fused_main(
    const float* __restrict__ edge, const __bf16* __restrict__ w1s,
    const __bf16* __restrict__ w2s, const float* __restrict__ Rt,
    const __bf16* __restrict__ Ctb, const float* __restrict__ b2,
    const float* __restrict__ W3, const float* __restrict__ b3,
    float* __restrict__ out) {
    __shared__ __bf16 w2lds[32768];              // 64 KB: W2 ksg 8..15, chunk-linear
    __shared__ unsigned int lds_e[128 * 34];     // 17.4 KB: 2 groups x [64 m][32 ep]
    __shared__ unsigned int lds_h1[2][64 * 140]; // 71.7 KB: per-group h1, stride 140 dw
    __shared__ float lds_c[512];                 // 2 KB: [0..255]=b2, [256..511]=W3

    const int tid = threadIdx.x;
    const int wid8 = tid >> 6;       // 0..7
    const int og   = wid8 & 3;       // och group (64 och)
    const int rw   = wid8 >> 2;      // row-group
    const int lane = tid & 63;
    const int p31  = lane & 31;
    const int hi   = lane >> 5;
    const int obase = og << 6;

    const int blk = blockIdx.x;      // 256 = 4b x 4m x 16 n-groups
    const int b   = blk >> 6;
    const int m0  = ((blk >> 4) & 3) << 6;
    const int n0  = (blk & 15) << 4; // 16 rows per block

    lds_c[tid] = (tid < 256) ? b2[tid] : W3[tid - 256];

    const float4* eg = (const float4*)edge;
    const int tid8 = tid & 255;      // within-group thread
    const int a_   = tid8 & 15;      // m-quad
    const int epb  = tid8 >> 4;      // 0..15 e-pair group
    float4 pf[4];

#define PREFETCH(nn)                                                        \
    {                                                                       \
        _Pragma("unroll")                                                   \
        for (int r = 0; r < 2; ++r) {                                       \
            int ep = r * 16 + epb;                                          \
            int f4 = (b * 64 + ep * 2) * 16384 + (nn) * 64 + (m0 >> 2) + a_;\
            pf[r * 2]     = eg[f4];                                         \
            pf[r * 2 + 1] = eg[f4 + 16384];                                 \
        }                                                                   \
    }

    // streamed W2 quarter (ksg 0..7): chunk = ((og*16 + q*4 + ksl)*2 + mb)
#define LOAD_Q(bf, q)                                                       \
    {                                                                       \
        _Pragma("unroll")                                                   \
        for (int ksl = 0; ksl < 4; ++ksl)                                   \
            _Pragma("unroll")                                               \
            for (int mb = 0; mb < 2; ++mb)                                  \
                A2q[bf][ksl][mb] = *(const bf16x8*)(w2_s +                  \
                    ((((og << 4) + (q) * 4 + ksl) << 1) + mb) * 512 + (lane << 3)); \
    }

    // ---- HBM edge prefetch FIRST (longest latency), then W2->LDS staging ----
    PREFETCH(n0 + rw);

    // ---- stage resident W2 half (ksg 8..15) into LDS, ONCE ----
    {
        bf16x8 wt[8];
#pragma unroll
        for (int i = 0; i < 8; ++i) {
            int rc = wid8 * 8 + i;                     // resident chunk 0..63
            int mb = rc & 1, k8 = (rc >> 1) & 7, wg = rc >> 4;
            int schunk = (((wg << 4) + 8 + k8) << 1) + mb;
            wt[i] = *(const bf16x8*)(w2s + schunk * 512 + (lane << 3));
        }
#pragma unroll
        for (int i = 0; i < 8; ++i)
            *(bf16x8*)(w2lds + (wid8 * 8 + i) * 512 + (lane << 3)) = wt[i];
    }

    // ---- hoisted it-invariant Ct fragments (32 regs; row-independent) ----
    bf16x4v CvR[8][2];
#pragma unroll
    for (int mb = 0; mb < 2; ++mb)
#pragma unroll
        for (int rg = 0; rg < 4; ++rg)
#pragma unroll
            for (int nb = 0; nb < 2; ++nb)
                CvR[mb * 4 + rg][nb] = *(const bf16x4v*)(Ctb +
                    ((b * 256 + m0 + nb * 32 + p31) << 8) + obase + mb * 32 + 8 * rg + 4 * hi);

    // ---- A1 (W1e) fragments: loop-invariant, persist (32 regs) ----
    bf16x8 A1[2][4];
#pragma unroll
    for (int mb = 0; mb < 2; ++mb)
#pragma unroll
        for (int ks = 0; ks < 4; ++ks)
            A1[mb][ks] = *(const bf16x8*)(w1s +
                ((((og << 2) + ks) << 1) + mb) * 512 + (lane << 3));

    f32x16 acc[2][2];
    bf16x8 A2q[2][4][2];
#pragma unroll 1
    for (int itp = 0; itp < 8; ++itp) {
        const int n_r = n0 + itp * 2 + rw;   // this wave's row

        // opaque per-iteration values: defeat LICM/CSE of streamed W2 loads
        // and of the it-invariant resident LDS reads (hoist = reg blowup)
        uint64_t w2a = (uint64_t)w2s;
        asm volatile("" : "+s"(w2a));
        const __bf16* w2_s = (const __bf16*)w2a;
        int koff = 0;
        asm volatile("" : "+v"(koff));

        // ---- stage pf -> lds_e (transpose to [m][e-pair], bf16), own row ----
#pragma unroll
        for (int r = 0; r < 2; ++r) {
            int ep = r * 16 + epb;
            const float* p0 = (const float*)&pf[r * 2];
            const float* p1 = (const float*)&pf[r * 2 + 1];
#pragma unroll
            for (int i = 0; i < 4; ++i) {
                union { __bf16 h[2]; unsigned int u; } t;
                t.h[0] = (__bf16)p0[i];
                t.h[1] = (__bf16)p1[i];
                lds_e[(rw * 64 + a_ * 4 + i) * 34 + ep] = t.u;
            }
        }
        // ---- next-pair HBM prefetch issued EARLY (flies across barriers) ----
        if (itp < 7) PREFETCH(n0 + (itp + 1) * 2 + rw);

        // ---- Rt row (L2 broadcast), consumed in epilogue 1 ----
        const int nRow = (b * 256 + n_r) << 8;
        f32x4t Rv[2][4];
#pragma unroll
        for (int mb = 0; mb < 2; ++mb)
#pragma unroll
            for (int rg = 0; rg < 4; ++rg)
                Rv[mb][rg] = *(const f32x4t*)(Rt + nRow + obase + mb * 32 + 8 * rg + 4 * hi);

        // ---- acc1 preload = Ct (MFMA C-operand is a free adder) ----
#pragma unroll
        for (int mb = 0; mb < 2; ++mb)
#pragma unroll
            for (int nb = 0; nb < 2; ++nb)
#pragma unroll
                for (int rg = 0; rg < 4; ++rg)
#pragma unroll
                    for (int rr = 0; rr < 4; ++rr)
                        acc[mb][nb][rg * 4 + rr] = (float)CvR[mb * 4 + rg][nb][rr];

        lds_barrier();

        // ---- layer 1: W1e(64K) @ edge (own row) ----
        __builtin_amdgcn_s_setprio(1);
#pragma unroll
        for (int ks = 0; ks < 4; ++ks) {
            bf16x8 B1[2];
#pragma unroll
            for (int nb = 0; nb < 2; ++nb) {
                union { u32x2 d[2]; bf16x8 v; } bb;
                const unsigned int* base = &lds_e[(rw * 64 + nb * 32 + p31) * 34 + ks * 8 + hi * 4];
                bb.d[0] = *(const u32x2*)base;
                bb.d[1] = *(const u32x2*)(base + 2);
                B1[nb] = bb.v;
            }
#pragma unroll
            for (int mb = 0; mb < 2; ++mb) {
                acc[mb][0] = __builtin_amdgcn_mfma_f32_32x32x16_bf16(A1[mb][ks], B1[0], acc[mb][0], 0, 0, 0);
                acc[mb][1] = __builtin_amdgcn_mfma_f32_32x32x16_bf16(A1[mb][ks], B1[1], acc[mb][1], 0, 0, 0);
            }
        }
        __builtin_amdgcn_s_setprio(0);

        // ---- epilogue 1: relu(acc + Rt) -> lds_h1[rw] ----
#pragma unroll
        for (int mb = 0; mb < 2; ++mb) {
#pragma unroll
            for (int rg = 0; rg < 4; ++rg) {
                int och = obase + mb * 32 + 8 * rg + 4 * hi;
                f32x4t Rvv = Rv[mb][rg];
#pragma unroll
                for (int nb = 0; nb < 2; ++nb) {
                    int pix = nb * 32 + p31;
                    union { __bf16 h[4]; u32x2 u; } t;
#pragma unroll
                    for (int rr = 0; rr < 4; ++rr) {
                        float v = acc[mb][nb][rg * 4 + rr] + Rvv[rr];
                        t.h[rr] = (__bf16)fmaxf(v, 0.f);
                    }
                    *(u32x2*)&lds_h1[rw][pix * 140 + (och >> 1)] = t.u;
                }
            }
        }
        // ---- streamed W2 quarter-0 prefetch, overlaps the barrier ----
        LOAD_Q(0, 0);

        // ---- acc2 preload = b2 ----
#pragma unroll
        for (int mb = 0; mb < 2; ++mb)
#pragma unroll
            for (int rg = 0; rg < 4; ++rg) {
                f32x4t b2v = *(const f32x4t*)&lds_c[obase + mb * 32 + 8 * rg + 4 * hi];
#pragma unroll
                for (int nb = 0; nb < 2; ++nb)
#pragma unroll
                    for (int rr = 0; rr < 4; ++rr)
                        acc[mb][nb][rg * 4 + rr] = b2v[rr];
            }

        lds_barrier();

        // ---- layer 2: ksg 0..7 streamed (rolling dbuf), 8..15 LDS-resident ----
        __builtin_amdgcn_s_setprio(1);
#pragma unroll
        for (int q = 0; q < 2; ++q) {
            if (q == 0) LOAD_Q(1, 1);
#pragma unroll
            for (int ksl = 0; ksl < 4; ++ksl) {
                const int ksg = q * 4 + ksl;
                bf16x8 B2[2];
#pragma unroll
                for (int nb = 0; nb < 2; ++nb)
                    B2[nb] = *(const bf16x8*)&lds_h1[rw][(nb * 32 + p31) * 140 + ksg * 8 + hi * 4];
#pragma unroll
                for (int mb = 0; mb < 2; ++mb) {
                    acc[mb][0] = __builtin_amdgcn_mfma_f32_32x32x16_bf16(A2q[q][ksl][mb], B2[0], acc[mb][0], 0, 0, 0);
                    acc[mb][1] = __builtin_amdgcn_mfma_f32_32x32x16_bf16(A2q[q][ksl][mb], B2[1], acc[mb][1], 0, 0, 0);
                }
            }
        }
#pragma unroll
        for (int k8 = 0; k8 < 8; ++k8) {
            const int ksg = 8 + k8;
            bf16x8 A2r[2];
#pragma unroll
            for (int mb = 0; mb < 2; ++mb)
                A2r[mb] = *(const bf16x8*)(w2lds +
                    (((og * 8 + k8) * 2 + mb) * 512 + koff) + (lane << 3));
            bf16x8 B2[2];
#pragma unroll
            for (int nb = 0; nb < 2; ++nb)
                B2[nb] = *(const bf16x8*)&lds_h1[rw][(nb * 32 + p31) * 140 + ksg * 8 + hi * 4];
#pragma unroll
            for (int mb = 0; mb < 2; ++mb) {
                acc[mb][0] = __builtin_amdgcn_mfma_f32_32x32x16_bf16(A2r[mb], B2[0], acc[mb][0], 0, 0, 0);
                acc[mb][1] = __builtin_amdgcn_mfma_f32_32x32x16_bf16(A2r[mb], B2[1], acc[mb][1], 0, 0, 0);
            }
        }
        __builtin_amdgcn_s_setprio(0);

        // ---- epilogue 2: relu, dot W3, shfl-combine, atomicAdd out ----
        float part0 = 0.f, part1 = 0.f;
#pragma unroll
        for (int mb = 0; mb < 2; ++mb) {
#pragma unroll
            for (int rg = 0; rg < 4; ++rg) {
                int och = obase + mb * 32 + 8 * rg + 4 * hi;
                f32x4t w3v = *(const f32x4t*)&lds_c[256 + och];
#pragma unroll
                for (int rr = 0; rr < 4; ++rr) {
                    float h0 = fmaxf(acc[mb][0][rg * 4 + rr], 0.f);
                    float h1v = fmaxf(acc[mb][1][rg * 4 + rr], 0.f);
                    part0 = fmaf(w3v[rr], h0, part0);
                    part1 = fmaf(w3v[rr], h1v, part1);
                }
            }
        }
        // combine hi halves (och 0..31 vs 32..63 of this wave's slice)
        part0 += __shfl_xor(part0, 32);
        part1 += __shfl_xor(part1, 32);
        {
            int pix = hi ? (32 + p31) : p31;
            float v = hi ? part1 : part0;
            atomicAdd(&out[((b * 256 + n_r) << 8) + m0 + pix], v);
        }
    }
#undef PREFETCH
#undef LOAD_Q
}

extern "C" void kernel_launch(void* const* d_in, const int* in_sizes, int n_in,
                              void* d_out, int out_size, void* d_ws, size_t ws_size,
                              hipStream_t stream) {
    const float* edge = (const float*)d_in[0];
    const float* node = (const float*)d_in[1];
    const float* W1   = (const float*)d_in[2];
    const float* b1   = (const float*)d_in[3];
    const float* W2   = (const float*)d_in[4];
    const float* b2   = (const float*)d_in[5];
    const float* W3   = (const float*)d_in[6];
    const float* b3   = (const float*)d_in[7];
    char* ws = (char*)d_ws;
    __bf16* w1s = (__bf16*)(ws + WS_W1S);
    __bf16* w2s = (__bf16*)(ws + WS_W2S);
    float*  Rt  = (float*)(ws + WS_R);
    __bf16* Ctb = (__bf16*)(ws + WS_CT);
    float* outp = (float*)d_out;

    prep_all<<<424, 256, 0, stream>>>(W1, b1, W2, node, b3, w1s, w2s, Rt, Ctb, outp);
    fused_main<<<256, 512, 0, stream>>>(edge, w1s, w2s, Rt, Ctb, b2, W3, b3, outp);
}

// Round 10
// 141.382 us; speedup vs baseline: 1.1778x; 1.0333x over previous
//
#include <hip/hip_runtime.h>
#include <stdint.h>

typedef __bf16 bf16x8 __attribute__((ext_vector_type(8)));
typedef __bf16 bf16x4v __attribute__((ext_vector_type(4)));
typedef float  f32x16 __attribute__((ext_vector_type(16)));
typedef float  f32x4t __attribute__((ext_vector_type(4)));
typedef unsigned int u32x2 __attribute__((ext_vector_type(2)));

// ---- ws layout (bytes) ----
#define WS_W1S 0            // 32 chunks  * 1 KB = 32 KB   W1e fragment-swizzled
#define WS_W2S 32768        // 128 chunks * 1 KB = 128 KB  W2 fragment-swizzled
#define WS_R   163840       // 4*256*256 f32 = 1 MiB   Rt[b][n][o] (incl. b1)
#define WS_CT  1212416      // 4*256*256 bf16 = 512 KB Ct[b][m][o]

// ---------------- merged pre-kernel: weights + rank-1 + out-init ----------
// (unchanged from R9)
__global__ __launch_bounds__(256) void prep_all(
    const float* __restrict__ W1, const float* __restrict__ b1,
    const float* __restrict__ W2, const float* __restrict__ node,
    const float* __restrict__ b3, __bf16* __restrict__ w1s,
    __bf16* __restrict__ w2s, float* __restrict__ Rt,
    __bf16* __restrict__ Ctb, float* __restrict__ out) {
    __shared__ float nds[128 * 8];
    const int blk = blockIdx.x;
    if (blk >= 168) {                         // ---- out-init: 256 blk x 1KB ----
        float v = b3[0];
        float4 f4 = make_float4(v, v, v, v);
        *(float4*)(out + (blk - 168) * 1024 + threadIdx.x * 4) = f4;
        return;
    }
    if (blk < 40) {                           // ---- weight swizzle part ----
        int t = blk * 256 + threadIdx.x;      // 40*256 = 160 chunks * 64 lanes
        int chunk = t >> 6, lane = t & 63;
        if (chunk < 128) {                    // W2: 4 wid x 16 ks x 2 mb
            int wid = chunk >> 5, ks = (chunk >> 1) & 15, mb = chunk & 1;
            int o = wid * 64 + mb * 32 + (lane & 31);
            int k = ks * 16 + (lane >> 5) * 8;
            const float* src = W2 + o * 256 + k;
            __bf16* dst = w2s + chunk * 512 + lane * 8;
#pragma unroll
            for (int j = 0; j < 8; ++j) dst[j] = (__bf16)src[j];
        } else if (chunk < 160) {             // W1e: 4 wid x 4 ks x 2 mb
            int c1 = chunk - 128;
            int wid = c1 >> 3, ks = (c1 >> 1) & 3, mb = c1 & 1;
            int o = wid * 64 + mb * 32 + (lane & 31);
            int k = ks * 16 + (lane >> 5) * 8;
            const float* src = W1 + o * 320 + k;
            __bf16* dst = w1s + c1 * 512 + lane * 8;
#pragma unroll
            for (int j = 0; j < 8; ++j) dst[j] = (__bf16)src[j];
        }
        return;
    }
    // ---- rank-1 part: rcb = b*32 + jg, 8 j per thread, o = tid ----
    const int rcb = blk - 40;                 // 0..127
    const int b = rcb >> 5, j0 = (rcb & 31) << 3;
    const int o = threadIdx.x;
    {
        int c = o >> 1, jh = (o & 1) * 4;
        *(float4*)&nds[c * 8 + jh] = *(const float4*)(node + b * 32768 + c * 256 + j0 + jh);
    }
    __syncthreads();
    float aR[8], aC[8];
#pragma unroll
    for (int j = 0; j < 8; ++j) { aR[j] = 0.f; aC[j] = 0.f; }
    const float* wr = W1 + o * 320 + 64;
    const float* wc = W1 + o * 320 + 192;
    for (int c4 = 0; c4 < 32; ++c4) {
        float4 wrv = *(const float4*)(wr + c4 * 4);
        float4 wcv = *(const float4*)(wc + c4 * 4);
        const float* wrp = (const float*)&wrv;
        const float* wcp = (const float*)&wcv;
#pragma unroll
        for (int r = 0; r < 4; ++r) {
            const f32x4t* nrow = (const f32x4t*)&nds[(c4 * 4 + r) * 8];
            f32x4t n0 = nrow[0], n1 = nrow[1];
#pragma unroll
            for (int q = 0; q < 4; ++q) {
                aR[q]     = fmaf(wrp[r], n0[q], aR[q]);
                aR[q + 4] = fmaf(wrp[r], n1[q], aR[q + 4]);
                aC[q]     = fmaf(wcp[r], n0[q], aC[q]);
                aC[q + 4] = fmaf(wcp[r], n1[q], aC[q + 4]);
            }
        }
    }
    float bb = b1[o];
#pragma unroll
    for (int j = 0; j < 8; ++j) {
        int idx = ((b * 256 + j0 + j) << 8) + o;
        Rt[idx] = aR[j] + bb;
        Ctb[idx] = (__bf16)aC[j];
    }
}

// ---------------- main fused kernel ----------------
// R10: producer-consumer wave specialization. R9 accounting: MFMA 30% + VALU
// 25% + LDS 33% ~= 88% of wall -> pipes SERIALIZED because all waves share
// each phase (lockstep). Fix that kept ONE barrier/row (R8's failure was 2x
// barriers): waves 0..3 = PRODUCERS (stage edge + L1 + epi1 -> h1), waves
// 4..7 = CONSUMERS (L2 + epi2 + atomicAdd). Each runs its OWN loop arriving
// at the block-wide s_barrier the SAME number of times (17); branch is
// wave-uniform so raw s_barrier arrival-count semantics apply. One producer +
// one consumer per SIMD: consumer MFMA (2048cy/step) overlaps producer VALU.
// KEY register win: a consumer needs no A1/CvR/pf, so its ENTIRE W2 och-slice
// fits in regs (32x bf16x8 = 128 VGPR) + acc 64 ~= 217 < 256 budget -> W2
// L2 streaming AND the 64 KB LDS residence both eliminated. LDS = 91 KB.
// Pipeline: producer writes h1[s&1] between barriers #s,#s+1; consumer reads
// row s between #s+1,#s+2 (lgkm drained at every arrival -> the rewrite of
// h1[s&1] after #s+2 cannot pass outstanding reads). lds_e double-buffered,
// producers-only. Output: shfl_xor(32) + atomicAdd (out pre-init b3).
// SPILL TRIPWIRE: VGPR >= 250 or WRITE_SIZE >> 10 MB. SYNC TRIPWIRE: fail.
__device__ __forceinline__ void lds_barrier() {
    __builtin_amdgcn_sched_barrier(0);
    asm volatile("s_waitcnt lgkmcnt(0)" ::: "memory");
    __builtin_amdgcn_s_barrier();
    __builtin_amdgcn_sched_barrier(0);
}

__global__ __launch_bounds__(512, 2) void fused_main(
    const float* __restrict__ edge, const __bf16* __restrict__ w1s,
    const __bf16* __restrict__ w2s, const float* __restrict__ Rt,
    const __bf16* __restrict__ Ctb, const float* __restrict__ b2,
    const float* __restrict__ W3, const float* __restrict__ b3,
    float* __restrict__ out) {
    __shared__ unsigned int lds_e[2][64 * 34];   // 17.4 KB: dbuf edge rows
    __shared__ unsigned int lds_h1[2][64 * 140]; // 71.7 KB: dbuf h1, stride 140 dw
    __shared__ float lds_c[512];                 // 2 KB: [0..255]=b2, [256..511]=W3

    const int tid = threadIdx.x;
    const int wid8 = tid >> 6;       // 0..7; 0..3 producers, 4..7 consumers
    const int lane = tid & 63;
    const int p31  = lane & 31;
    const int hi   = lane >> 5;

    const int blk = blockIdx.x;      // 256 = 4b x 4m x 16 n-groups
    const int b   = blk >> 6;
    const int m0  = ((blk >> 4) & 3) << 6;
    const int n0  = (blk & 15) << 4; // 16 rows per block

    lds_c[tid] = (tid < 256) ? b2[tid] : W3[tid - 256];

    if (wid8 < 4) {
        // ================= PRODUCER (4 waves, tid 0..255) =================
        const int og = wid8;
        const int obase = og << 6;
        const float4* eg = (const float4*)edge;
        const int a_  = tid & 15;    // m-quad
        const int epb = tid >> 4;    // 0..15 e-pair group
        float4 pf[4];

#define PREFETCH(nn)                                                        \
    {                                                                       \
        _Pragma("unroll")                                                   \
        for (int r = 0; r < 2; ++r) {                                       \
            int ep = r * 16 + epb;                                          \
            int f4 = (b * 64 + ep * 2) * 16384 + (nn) * 64 + (m0 >> 2) + a_;\
            pf[r * 2]     = eg[f4];                                         \
            pf[r * 2 + 1] = eg[f4 + 16384];                                 \
        }                                                                   \
    }
#define STAGE(bufidx)                                                       \
    {                                                                       \
        _Pragma("unroll")                                                   \
        for (int r = 0; r < 2; ++r) {                                       \
            int ep = r * 16 + epb;                                          \
            const float* p0 = (const float*)&pf[r * 2];                     \
            const float* p1 = (const float*)&pf[r * 2 + 1];                 \
            _Pragma("unroll")                                               \
            for (int i = 0; i < 4; ++i) {                                   \
                union { __bf16 h[2]; unsigned int u; } t;                   \
                t.h[0] = (__bf16)p0[i];                                     \
                t.h[1] = (__bf16)p1[i];                                     \
                lds_e[bufidx][(a_ * 4 + i) * 34 + ep] = t.u;                \
            }                                                               \
        }                                                                   \
    }

        PREFETCH(n0);

        // it-invariant Ct fragments (32 regs)
        bf16x4v CvR[8][2];
#pragma unroll
        for (int mb = 0; mb < 2; ++mb)
#pragma unroll
            for (int rg = 0; rg < 4; ++rg)
#pragma unroll
                for (int nb = 0; nb < 2; ++nb)
                    CvR[mb * 4 + rg][nb] = *(const bf16x4v*)(Ctb +
                        ((b * 256 + m0 + nb * 32 + p31) << 8) + obase + mb * 32 + 8 * rg + 4 * hi);

        // A1 (W1e) fragments: persist (32 regs)
        bf16x8 A1[2][4];
#pragma unroll
        for (int mb = 0; mb < 2; ++mb)
#pragma unroll
            for (int ks = 0; ks < 4; ++ks)
                A1[mb][ks] = *(const bf16x8*)(w1s +
                    ((((og << 2) + ks) << 1) + mb) * 512 + (lane << 3));

        STAGE(0);                    // row 0 -> lds_e[0]
        PREFETCH(n0 + 1);
        lds_barrier();               // arrival #0 (seals lds_e[0], lds_c)

        f32x16 acc[2][2];
#pragma unroll 1
        for (int s = 0; s < 16; ++s) {
            const int buf = s & 1;
            const int n_r = n0 + s;
            const int nRow = (b * 256 + n_r) << 8;

            // Rt row (L2 broadcast) issued early; consumed in epi1
            f32x4t Rv[2][4];
#pragma unroll
            for (int mb = 0; mb < 2; ++mb)
#pragma unroll
                for (int rg = 0; rg < 4; ++rg)
                    Rv[mb][rg] = *(const f32x4t*)(Rt + nRow + obase + mb * 32 + 8 * rg + 4 * hi);

            // acc = Ct preload (MFMA C-operand is a free adder)
#pragma unroll
            for (int mb = 0; mb < 2; ++mb)
#pragma unroll
                for (int nb = 0; nb < 2; ++nb)
#pragma unroll
                    for (int rg = 0; rg < 4; ++rg)
#pragma unroll
                        for (int rr = 0; rr < 4; ++rr)
                            acc[mb][nb][rg * 4 + rr] = (float)CvR[mb * 4 + rg][nb][rr];

            // layer 1 from lds_e[buf] (staged last step, sealed by barrier #s)
#pragma unroll
            for (int ks = 0; ks < 4; ++ks) {
                bf16x8 B1[2];
#pragma unroll
                for (int nb = 0; nb < 2; ++nb) {
                    union { u32x2 d[2]; bf16x8 v; } bb;
                    const unsigned int* base = &lds_e[buf][(nb * 32 + p31) * 34 + ks * 8 + hi * 4];
                    bb.d[0] = *(const u32x2*)base;
                    bb.d[1] = *(const u32x2*)(base + 2);
                    B1[nb] = bb.v;
                }
#pragma unroll
                for (int mb = 0; mb < 2; ++mb) {
                    acc[mb][0] = __builtin_amdgcn_mfma_f32_32x32x16_bf16(A1[mb][ks], B1[0], acc[mb][0], 0, 0, 0);
                    acc[mb][1] = __builtin_amdgcn_mfma_f32_32x32x16_bf16(A1[mb][ks], B1[1], acc[mb][1], 0, 0, 0);
                }
            }

            // epilogue 1: relu(acc + Rt) -> lds_h1[buf]
#pragma unroll
            for (int mb = 0; mb < 2; ++mb) {
#pragma unroll
                for (int rg = 0; rg < 4; ++rg) {
                    int och = obase + mb * 32 + 8 * rg + 4 * hi;
                    f32x4t Rvv = Rv[mb][rg];
#pragma unroll
                    for (int nb = 0; nb < 2; ++nb) {
                        int pix = nb * 32 + p31;
                        union { __bf16 h[4]; u32x2 u; } t;
#pragma unroll
                        for (int rr = 0; rr < 4; ++rr) {
                            float v = acc[mb][nb][rg * 4 + rr] + Rvv[rr];
                            t.h[rr] = (__bf16)fmaxf(v, 0.f);
                        }
                        *(u32x2*)&lds_h1[buf][pix * 140 + (och >> 1)] = t.u;
                    }
                }
            }

            // stage next row into the other edge buffer; prefetch row s+2
            if (s < 15) STAGE(buf ^ 1);
            if (s < 14) PREFETCH(n0 + s + 2);

            lds_barrier();           // arrival #(s+1)
        }
#undef PREFETCH
#undef STAGE
    } else {
        // ================= CONSUMER (4 waves, tid 256..511) ===============
        const int og = wid8 - 4;
        const int obase = og << 6;

        // ENTIRE W2 och-slice in registers: 16 ksg x 2 mb bf16x8 = 128 VGPR.
        // (Only possible because this wave does no L1/stage work -- the
        // specialization IS the register budget.)
        bf16x8 A2f[16][2];
#pragma unroll
        for (int ksg = 0; ksg < 16; ++ksg)
#pragma unroll
            for (int mb = 0; mb < 2; ++mb)
                A2f[ksg][mb] = *(const bf16x8*)(w2s +
                    ((((og << 4) + ksg) << 1) + mb) * 512 + (lane << 3));

        lds_barrier();               // arrival #0

        f32x16 acc[2][2];
#pragma unroll 1
        for (int s = 0; s < 16; ++s) {
            lds_barrier();           // arrival #(s+1): h1[row s] now sealed
            const int buf = s & 1;
            const int n_r = n0 + s;

            // acc = b2 preload
#pragma unroll
            for (int mb = 0; mb < 2; ++mb)
#pragma unroll
                for (int rg = 0; rg < 4; ++rg) {
                    f32x4t b2v = *(const f32x4t*)&lds_c[obase + mb * 32 + 8 * rg + 4 * hi];
#pragma unroll
                    for (int nb = 0; nb < 2; ++nb)
#pragma unroll
                        for (int rr = 0; rr < 4; ++rr)
                            acc[mb][nb][rg * 4 + rr] = b2v[rr];
                }

            // layer 2: all 16 ksg from registers, B2 from lds_h1[buf]
            __builtin_amdgcn_s_setprio(1);
#pragma unroll
            for (int ksg = 0; ksg < 16; ++ksg) {
                bf16x8 B2[2];
#pragma unroll
                for (int nb = 0; nb < 2; ++nb)
                    B2[nb] = *(const bf16x8*)&lds_h1[buf][(nb * 32 + p31) * 140 + ksg * 8 + hi * 4];
#pragma unroll
                for (int mb = 0; mb < 2; ++mb) {
                    acc[mb][0] = __builtin_amdgcn_mfma_f32_32x32x16_bf16(A2f[ksg][mb], B2[0], acc[mb][0], 0, 0, 0);
                    acc[mb][1] = __builtin_amdgcn_mfma_f32_32x32x16_bf16(A2f[ksg][mb], B2[1], acc[mb][1], 0, 0, 0);
                }
            }
            __builtin_amdgcn_s_setprio(0);

            // epilogue 2: relu, dot W3, shfl-combine, atomicAdd out
            float part0 = 0.f, part1 = 0.f;
#pragma unroll
            for (int mb = 0; mb < 2; ++mb) {
#pragma unroll
                for (int rg = 0; rg < 4; ++rg) {
                    int och = obase + mb * 32 + 8 * rg + 4 * hi;
                    f32x4t w3v = *(const f32x4t*)&lds_c[256 + och];
#pragma unroll
                    for (int rr = 0; rr < 4; ++rr) {
                        float h0 = fmaxf(acc[mb][0][rg * 4 + rr], 0.f);
                        float h1v = fmaxf(acc[mb][1][rg * 4 + rr], 0.f);
                        part0 = fmaf(w3v[rr], h0, part0);
                        part1 = fmaf(w3v[rr], h1v, part1);
                    }
                }
            }
            part0 += __shfl_xor(part0, 32);
            part1 += __shfl_xor(part1, 32);
            {
                int pix = hi ? (32 + p31) : p31;
                float v = hi ? part1 : part0;
                atomicAdd(&out[((b * 256 + n_r) << 8) + m0 + pix], v);
            }
        }
    }
}

extern "C" void kernel_launch(void* const* d_in, const int* in_sizes, int n_in,
                              void* d_out, int out_size, void* d_ws, size_t ws_size,
                              hipStream_t stream) {
    const float* edge = (const float*)d_in[0];
    const float* node = (const float*)d_in[1];
    const float* W1   = (const float*)d_in[2];
    const float* b1   = (const float*)d_in[3];
    const float* W2   = (const float*)d_in[4];
    const float* b2   = (const float*)d_in[5];
    const float* W3   = (const float*)d_in[6];
    const float* b3   = (const float*)d_in[7];
    char* ws = (char*)d_ws;
    __bf16* w1s = (__bf16*)(ws + WS_W1S);
    __bf16* w2s = (__bf16*)(ws + WS_W2S);
    float*  Rt  = (float*)(ws + WS_R);
    __bf16* Ctb = (__bf16*)(ws + WS_CT);
    float* outp = (float*)d_out;

    prep_all<<<424, 256, 0, stream>>>(W1, b1, W2, node, b3, w1s, w2s, Rt, Ctb, outp);
    fused_main<<<256, 512, 0, stream>>>(edge, w1s, w2s, Rt, Ctb, b2, W3, b3, outp);
}

// Round 11
// 141.005 us; speedup vs baseline: 1.1809x; 1.0027x over previous
//
#include <hip/hip_runtime.h>
#include <stdint.h>

typedef __bf16 bf16x8 __attribute__((ext_vector_type(8)));
typedef __bf16 bf16x4v __attribute__((ext_vector_type(4)));
typedef float  f32x16 __attribute__((ext_vector_type(16)));
typedef float  f32x4t __attribute__((ext_vector_type(4)));
typedef unsigned int u32x2 __attribute__((ext_vector_type(2)));

// ---- ws layout (bytes) ----
#define WS_W1S 0            // 32 chunks  * 1 KB = 32 KB   W1e fragment-swizzled
#define WS_W2S 32768        // 128 chunks * 1 KB = 128 KB  W2 fragment-swizzled
#define WS_R   163840       // 4*256*256 f32 = 1 MiB   Rt[b][n][o] (incl. b1)
#define WS_CT  1212416      // 4*256*256 bf16 = 512 KB Ct[b][m][o]

// ---------------- merged pre-kernel: weights + rank-1 + out-init ----------
// (unchanged from R9/R10)
__global__ __launch_bounds__(256) void prep_all(
    const float* __restrict__ W1, const float* __restrict__ b1,
    const float* __restrict__ W2, const float* __restrict__ node,
    const float* __restrict__ b3, __bf16* __restrict__ w1s,
    __bf16* __restrict__ w2s, float* __restrict__ Rt,
    __bf16* __restrict__ Ctb, float* __restrict__ out) {
    __shared__ float nds[128 * 8];
    const int blk = blockIdx.x;
    if (blk >= 168) {                         // ---- out-init: 256 blk x 1KB ----
        float v = b3[0];
        float4 f4 = make_float4(v, v, v, v);
        *(float4*)(out + (blk - 168) * 1024 + threadIdx.x * 4) = f4;
        return;
    }
    if (blk < 40) {                           // ---- weight swizzle part ----
        int t = blk * 256 + threadIdx.x;      // 40*256 = 160 chunks * 64 lanes
        int chunk = t >> 6, lane = t & 63;
        if (chunk < 128) {                    // W2: 4 wid x 16 ks x 2 mb
            int wid = chunk >> 5, ks = (chunk >> 1) & 15, mb = chunk & 1;
            int o = wid * 64 + mb * 32 + (lane & 31);
            int k = ks * 16 + (lane >> 5) * 8;
            const float* src = W2 + o * 256 + k;
            __bf16* dst = w2s + chunk * 512 + lane * 8;
#pragma unroll
            for (int j = 0; j < 8; ++j) dst[j] = (__bf16)src[j];
        } else if (chunk < 160) {             // W1e: 4 wid x 4 ks x 2 mb
            int c1 = chunk - 128;
            int wid = c1 >> 3, ks = (c1 >> 1) & 3, mb = c1 & 1;
            int o = wid * 64 + mb * 32 + (lane & 31);
            int k = ks * 16 + (lane >> 5) * 8;
            const float* src = W1 + o * 320 + k;
            __bf16* dst = w1s + c1 * 512 + lane * 8;
#pragma unroll
            for (int j = 0; j < 8; ++j) dst[j] = (__bf16)src[j];
        }
        return;
    }
    // ---- rank-1 part: rcb = b*32 + jg, 8 j per thread, o = tid ----
    const int rcb = blk - 40;                 // 0..127
    const int b = rcb >> 5, j0 = (rcb & 31) << 3;
    const int o = threadIdx.x;
    {
        int c = o >> 1, jh = (o & 1) * 4;
        *(float4*)&nds[c * 8 + jh] = *(const float4*)(node + b * 32768 + c * 256 + j0 + jh);
    }
    __syncthreads();
    float aR[8], aC[8];
#pragma unroll
    for (int j = 0; j < 8; ++j) { aR[j] = 0.f; aC[j] = 0.f; }
    const float* wr = W1 + o * 320 + 64;
    const float* wc = W1 + o * 320 + 192;
    for (int c4 = 0; c4 < 32; ++c4) {
        float4 wrv = *(const float4*)(wr + c4 * 4);
        float4 wcv = *(const float4*)(wc + c4 * 4);
        const float* wrp = (const float*)&wrv;
        const float* wcp = (const float*)&wcv;
#pragma unroll
        for (int r = 0; r < 4; ++r) {
            const f32x4t* nrow = (const f32x4t*)&nds[(c4 * 4 + r) * 8];
            f32x4t n0 = nrow[0], n1 = nrow[1];
#pragma unroll
            for (int q = 0; q < 4; ++q) {
                aR[q]     = fmaf(wrp[r], n0[q], aR[q]);
                aR[q + 4] = fmaf(wrp[r], n1[q], aR[q + 4]);
                aC[q]     = fmaf(wcp[r], n0[q], aC[q]);
                aC[q + 4] = fmaf(wcp[r], n1[q], aC[q + 4]);
            }
        }
    }
    float bb = b1[o];
#pragma unroll
    for (int j = 0; j < 8; ++j) {
        int idx = ((b * 256 + j0 + j) << 8) + o;
        Rt[idx] = aR[j] + bb;
        Ctb[idx] = (__bf16)aC[j];
    }
}

// ---------------- main fused kernel ----------------
// R11 = R10 producer-consumer structure + SOFTWARE-PIPELINED PREAMBLES.
// R10 post-mortem: both roles carried barrier-independent preamble work
// (producer: Rt L2 load + Ct->acc preload; consumer: b2->acc preload) on the
// POST-barrier critical path -- and lds_barrier's sched_barrier(0) pins it
// there. R11 moves each preamble to the PRE-barrier slack of the previous
// step (same 17 barriers, same hazards): steps now open directly with MFMAs.
// Producer holds next-step Rv across the barrier (+32 VGPR, ~220 unified of
// 256 budget). Consumer's FIRST b2 preload is placed after barrier #0
// (lds_c not sealed earlier -- race avoided); subsequent preloads follow
// epi2, and lds_c is read-only after #0.
// Structure recap (R10): waves 0..3 producers (stage edge + L1 + epi1->h1),
// waves 4..7 consumers (entire W2 och-slice in 128 VGPRs -> zero W2 traffic
// in loop; L2 + epi2 + atomicAdd). One barrier per row; wave-uniform branch,
// equal s_barrier arrival counts (17 each). LDS 91 KB. Out pre-init b3.
// SPILL TRIPWIRE: VGPR >= 250 or WRITE_SIZE >> 10 MB. SYNC TRIPWIRE: fail.
__device__ __forceinline__ void lds_barrier() {
    __builtin_amdgcn_sched_barrier(0);
    asm volatile("s_waitcnt lgkmcnt(0)" ::: "memory");
    __builtin_amdgcn_s_barrier();
    __builtin_amdgcn_sched_barrier(0);
}

__global__ __launch_bounds__(512, 2) void fused_main(
    const float* __restrict__ edge, const __bf16* __restrict__ w1s,
    const __bf16* __restrict__ w2s, const float* __restrict__ Rt,
    const __bf16* __restrict__ Ctb, const float* __restrict__ b2,
    const float* __restrict__ W3, const float* __restrict__ b3,
    float* __restrict__ out) {
    __shared__ unsigned int lds_e[2][64 * 34];   // 17.4 KB: dbuf edge rows
    __shared__ unsigned int lds_h1[2][64 * 140]; // 71.7 KB: dbuf h1, stride 140 dw
    __shared__ float lds_c[512];                 // 2 KB: [0..255]=b2, [256..511]=W3

    const int tid = threadIdx.x;
    const int wid8 = tid >> 6;       // 0..7; 0..3 producers, 4..7 consumers
    const int lane = tid & 63;
    const int p31  = lane & 31;
    const int hi   = lane >> 5;

    const int blk = blockIdx.x;      // 256 = 4b x 4m x 16 n-groups
    const int b   = blk >> 6;
    const int m0  = ((blk >> 4) & 3) << 6;
    const int n0  = (blk & 15) << 4; // 16 rows per block

    lds_c[tid] = (tid < 256) ? b2[tid] : W3[tid - 256];

    if (wid8 < 4) {
        // ================= PRODUCER (4 waves, tid 0..255) =================
        const int og = wid8;
        const int obase = og << 6;
        const float4* eg = (const float4*)edge;
        const int a_  = tid & 15;    // m-quad
        const int epb = tid >> 4;    // 0..15 e-pair group
        float4 pf[4];

#define PREFETCH(nn)                                                        \
    {                                                                       \
        _Pragma("unroll")                                                   \
        for (int r = 0; r < 2; ++r) {                                       \
            int ep = r * 16 + epb;                                          \
            int f4 = (b * 64 + ep * 2) * 16384 + (nn) * 64 + (m0 >> 2) + a_;\
            pf[r * 2]     = eg[f4];                                         \
            pf[r * 2 + 1] = eg[f4 + 16384];                                 \
        }                                                                   \
    }
#define STAGE(bufidx)                                                       \
    {                                                                       \
        _Pragma("unroll")                                                   \
        for (int r = 0; r < 2; ++r) {                                       \
            int ep = r * 16 + epb;                                          \
            const float* p0 = (const float*)&pf[r * 2];                     \
            const float* p1 = (const float*)&pf[r * 2 + 1];                 \
            _Pragma("unroll")                                               \
            for (int i = 0; i < 4; ++i) {                                   \
                union { __bf16 h[2]; unsigned int u; } t;                   \
                t.h[0] = (__bf16)p0[i];                                     \
                t.h[1] = (__bf16)p1[i];                                     \
                lds_e[bufidx][(a_ * 4 + i) * 34 + ep] = t.u;                \
            }                                                               \
        }                                                                   \
    }
#define LOAD_RV(nn)                                                         \
    {                                                                       \
        const int nRow_ = (b * 256 + (nn)) << 8;                            \
        _Pragma("unroll")                                                   \
        for (int mb = 0; mb < 2; ++mb)                                      \
            _Pragma("unroll")                                               \
            for (int rg = 0; rg < 4; ++rg)                                  \
                Rv[mb][rg] = *(const f32x4t*)(Rt + nRow_ + obase + mb * 32 + 8 * rg + 4 * hi); \
    }
#define PRELOAD_CT()                                                        \
    {                                                                       \
        _Pragma("unroll")                                                   \
        for (int mb = 0; mb < 2; ++mb)                                      \
            _Pragma("unroll")                                               \
            for (int nb = 0; nb < 2; ++nb)                                  \
                _Pragma("unroll")                                           \
                for (int rg = 0; rg < 4; ++rg)                              \
                    _Pragma("unroll")                                       \
                    for (int rr = 0; rr < 4; ++rr)                          \
                        acc[mb][nb][rg * 4 + rr] = (float)CvR[mb * 4 + rg][nb][rr]; \
    }

        PREFETCH(n0);

        // it-invariant Ct fragments (32 regs)
        bf16x4v CvR[8][2];
#pragma unroll
        for (int mb = 0; mb < 2; ++mb)
#pragma unroll
            for (int rg = 0; rg < 4; ++rg)
#pragma unroll
                for (int nb = 0; nb < 2; ++nb)
                    CvR[mb * 4 + rg][nb] = *(const bf16x4v*)(Ctb +
                        ((b * 256 + m0 + nb * 32 + p31) << 8) + obase + mb * 32 + 8 * rg + 4 * hi);

        // A1 (W1e) fragments: persist (32 regs)
        bf16x8 A1[2][4];
#pragma unroll
        for (int mb = 0; mb < 2; ++mb)
#pragma unroll
            for (int ks = 0; ks < 4; ++ks)
                A1[mb][ks] = *(const bf16x8*)(w1s +
                    ((((og << 2) + ks) << 1) + mb) * 512 + (lane << 3));

        STAGE(0);                    // row 0 -> lds_e[0]
        PREFETCH(n0 + 1);

        // ---- step-0 preamble BEFORE barrier #0 (global/reg only, no LDS
        //      hazard): Rv(row 0) + acc=Ct ----
        f32x16 acc[2][2];
        f32x4t Rv[2][4];
        LOAD_RV(n0);
        PRELOAD_CT();

        lds_barrier();               // arrival #0 (seals lds_e[0], lds_c)

#pragma unroll 1
        for (int s = 0; s < 16; ++s) {
            const int buf = s & 1;

            // ---- layer 1 IMMEDIATELY (acc/Rv preloaded last step) ----
#pragma unroll
            for (int ks = 0; ks < 4; ++ks) {
                bf16x8 B1[2];
#pragma unroll
                for (int nb = 0; nb < 2; ++nb) {
                    union { u32x2 d[2]; bf16x8 v; } bb;
                    const unsigned int* base = &lds_e[buf][(nb * 32 + p31) * 34 + ks * 8 + hi * 4];
                    bb.d[0] = *(const u32x2*)base;
                    bb.d[1] = *(const u32x2*)(base + 2);
                    B1[nb] = bb.v;
                }
#pragma unroll
                for (int mb = 0; mb < 2; ++mb) {
                    acc[mb][0] = __builtin_amdgcn_mfma_f32_32x32x16_bf16(A1[mb][ks], B1[0], acc[mb][0], 0, 0, 0);
                    acc[mb][1] = __builtin_amdgcn_mfma_f32_32x32x16_bf16(A1[mb][ks], B1[1], acc[mb][1], 0, 0, 0);
                }
            }

            // ---- epilogue 1: relu(acc + Rt) -> lds_h1[buf] ----
#pragma unroll
            for (int mb = 0; mb < 2; ++mb) {
#pragma unroll
                for (int rg = 0; rg < 4; ++rg) {
                    int och = obase + mb * 32 + 8 * rg + 4 * hi;
                    f32x4t Rvv = Rv[mb][rg];
#pragma unroll
                    for (int nb = 0; nb < 2; ++nb) {
                        int pix = nb * 32 + p31;
                        union { __bf16 h[4]; u32x2 u; } t;
#pragma unroll
                        for (int rr = 0; rr < 4; ++rr) {
                            float v = acc[mb][nb][rg * 4 + rr] + Rvv[rr];
                            t.h[rr] = (__bf16)fmaxf(v, 0.f);
                        }
                        *(u32x2*)&lds_h1[buf][pix * 140 + (och >> 1)] = t.u;
                    }
                }
            }

            // ---- stage next row; prefetch row s+2; NEXT-step preamble
            //      (Rv(row s+1) + acc=Ct) all in pre-barrier slack ----
            if (s < 15) {
                STAGE(buf ^ 1);
                LOAD_RV(n0 + s + 1);
                PRELOAD_CT();
            }
            if (s < 14) PREFETCH(n0 + s + 2);

            lds_barrier();           // arrival #(s+1)
        }
#undef PREFETCH
#undef STAGE
#undef LOAD_RV
#undef PRELOAD_CT
    } else {
        // ================= CONSUMER (4 waves, tid 256..511) ===============
        const int og = wid8 - 4;
        const int obase = og << 6;

        // ENTIRE W2 och-slice in registers: 16 ksg x 2 mb bf16x8 = 128 VGPR.
        bf16x8 A2f[16][2];
#pragma unroll
        for (int ksg = 0; ksg < 16; ++ksg)
#pragma unroll
            for (int mb = 0; mb < 2; ++mb)
                A2f[ksg][mb] = *(const bf16x8*)(w2s +
                    ((((og << 4) + ksg) << 1) + mb) * 512 + (lane << 3));

        lds_barrier();               // arrival #0

#define PRELOAD_B2()                                                        \
    {                                                                       \
        _Pragma("unroll")                                                   \
        for (int mb = 0; mb < 2; ++mb)                                      \
            _Pragma("unroll")                                               \
            for (int rg = 0; rg < 4; ++rg) {                                \
                f32x4t b2v = *(const f32x4t*)&lds_c[obase + mb * 32 + 8 * rg + 4 * hi]; \
                _Pragma("unroll")                                           \
                for (int nb = 0; nb < 2; ++nb)                              \
                    _Pragma("unroll")                                       \
                    for (int rr = 0; rr < 4; ++rr)                          \
                        acc[mb][nb][rg * 4 + rr] = b2v[rr];                 \
            }                                                               \
    }

        // first b2 preload AFTER barrier #0 (lds_c sealed by #0); sits in
        // the slack while producers build row 0
        f32x16 acc[2][2];
        PRELOAD_B2();

#pragma unroll 1
        for (int s = 0; s < 16; ++s) {
            lds_barrier();           // arrival #(s+1): h1[row s] now sealed
            const int buf = s & 1;
            const int n_r = n0 + s;

            // ---- layer 2 IMMEDIATELY (acc preloaded pre-barrier) ----
            __builtin_amdgcn_s_setprio(1);
#pragma unroll
            for (int ksg = 0; ksg < 16; ++ksg) {
                bf16x8 B2[2];
#pragma unroll
                for (int nb = 0; nb < 2; ++nb)
                    B2[nb] = *(const bf16x8*)&lds_h1[buf][(nb * 32 + p31) * 140 + ksg * 8 + hi * 4];
#pragma unroll
                for (int mb = 0; mb < 2; ++mb) {
                    acc[mb][0] = __builtin_amdgcn_mfma_f32_32x32x16_bf16(A2f[ksg][mb], B2[0], acc[mb][0], 0, 0, 0);
                    acc[mb][1] = __builtin_amdgcn_mfma_f32_32x32x16_bf16(A2f[ksg][mb], B2[1], acc[mb][1], 0, 0, 0);
                }
            }
            __builtin_amdgcn_s_setprio(0);

            // ---- epilogue 2: relu, dot W3, shfl-combine, atomicAdd out ----
            float part0 = 0.f, part1 = 0.f;
#pragma unroll
            for (int mb = 0; mb < 2; ++mb) {
#pragma unroll
                for (int rg = 0; rg < 4; ++rg) {
                    int och = obase + mb * 32 + 8 * rg + 4 * hi;
                    f32x4t w3v = *(const f32x4t*)&lds_c[256 + och];
#pragma unroll
                    for (int rr = 0; rr < 4; ++rr) {
                        float h0 = fmaxf(acc[mb][0][rg * 4 + rr], 0.f);
                        float h1v = fmaxf(acc[mb][1][rg * 4 + rr], 0.f);
                        part0 = fmaf(w3v[rr], h0, part0);
                        part1 = fmaf(w3v[rr], h1v, part1);
                    }
                }
            }
            part0 += __shfl_xor(part0, 32);
            part1 += __shfl_xor(part1, 32);
            {
                int pix = hi ? (32 + p31) : p31;
                float v = hi ? part1 : part0;
                atomicAdd(&out[((b * 256 + n_r) << 8) + m0 + pix], v);
            }

            // ---- NEXT-step b2 preload in pre-barrier slack ----
            if (s < 15) PRELOAD_B2();
        }
#undef PRELOAD_B2
    }
}

extern "C" void kernel_launch(void* const* d_in, const int* in_sizes, int n_in,
                              void* d_out, int out_size, void* d_ws, size_t ws_size,
                              hipStream_t stream) {
    const float* edge = (const float*)d_in[0];
    const float* node = (const float*)d_in[1];
    const float* W1   = (const float*)d_in[2];
    const float* b1   = (const float*)d_in[3];
    const float* W2   = (const float*)d_in[4];
    const float* b2   = (const float*)d_in[5];
    const float* W3   = (const float*)d_in[6];
    const float* b3   = (const float*)d_in[7];
    char* ws = (char*)d_ws;
    __bf16* w1s = (__bf16*)(ws + WS_W1S);
    __bf16* w2s = (__bf16*)(ws + WS_W2S);
    float*  Rt  = (float*)(ws + WS_R);
    __bf16* Ctb = (__bf16*)(ws + WS_CT);
    float* outp = (float*)d_out;

    prep_all<<<424, 256, 0, stream>>>(W1, b1, W2, node, b3, w1s, w2s, Rt, Ctb, outp);
    fused_main<<<256, 512, 0, stream>>>(edge, w1s, w2s, Rt, Ctb, b2, W3, b3, outp);
}